// Round 8
// baseline (208.289 us; speedup 1.0000x reference)
//
#include <hip/hip_runtime.h>
#include <cmath>

// Flash attention fwd, MI355X (gfx950).
// B=2 H=16 S=2048 D=64, fp32 in/out, bf16 MFMA 16x16x32 internally.
//
// R8: barrier-free main loop. A pre-pass converts Q(scaled)/K to bf16 and V
//     to bf16 TRANSPOSED 64-key tiles [bh][tile][d][key] in d_ws. The main
//     kernel reads MFMA A-fragments directly from global (16B/lane dwordx4,
//     L1/L2-cached, register double-buffered one tile ahead) -> no K/V LDS
//     staging, no __syncthreads at all, no staging cvt VALU. LDS holds only
//     the wave-private Ps (P C-layout -> A-layout transpose). XCD-swizzled
//     1D grid puts all 16 q-tiles of one bh on one XCD (L2 locality).
//     R5's m=0 softmax retained (exact via shift-invariance).
//
// Verified-layout MFMA (m89/m91/m120):
//   A[m=lane&15][k=(lane>>4)*8+j], B[k=(lane>>4)*8+j][n=lane&15],
//   C/D: col=lane&15, row=(lane>>4)*4+reg.

#define S_LEN   2048
#define D_HEAD  64
#define NHEADS  16
#define NBH     32
#define TQ      128   // queries per block
#define TK      64    // keys per tile
#define NTILE   (S_LEN / TK)   // 32
#define LDSTR   72    // Ps row stride (bf16 elems)

typedef short bfrag8 __attribute__((ext_vector_type(8)));  // 8 bf16 (A/B frag)
typedef float f32x4  __attribute__((ext_vector_type(4)));  // C/D frag
typedef int   i32x2  __attribute__((ext_vector_type(2)));
typedef int   i32x4  __attribute__((ext_vector_type(4)));

static __device__ __forceinline__ short f2bf(float f) {
  unsigned int u = __builtin_bit_cast(unsigned int, f);
  u = (u + 0x7fffu + ((u >> 16) & 1u)) >> 16;
  return (short)(unsigned short)u;
}

static __device__ __forceinline__ int pk2bf(float a, float b) {
#if __has_builtin(__builtin_amdgcn_cvt_pk_bf16_f32)
  typedef __bf16 bf16x2 __attribute__((ext_vector_type(2)));
  bf16x2 r = __builtin_amdgcn_cvt_pk_bf16_f32(a, b);
  return __builtin_bit_cast(int, r);
#else
  return (int)(unsigned short)f2bf(a) | ((int)(unsigned short)f2bf(b) << 16);
#endif
}

static __device__ __forceinline__ float fexp2(float x) {
#if __has_builtin(__builtin_amdgcn_exp2f)
  return __builtin_amdgcn_exp2f(x);   // v_exp_f32
#else
  return exp2f(x);
#endif
}

// ---------------------------------------------------------------------------
// Pre-pass: per (tile, bh): Q fp32 -> bf16*qscale [bh][q][d];
// K fp32 -> bf16 [bh][key][d]; V fp32 -> bf16 transposed tiles
// [bh][tile][d][key64] (each tile a contiguous 64x64 bf16 block).
// ---------------------------------------------------------------------------
__global__ __launch_bounds__(256)
void fa_prep(const float* __restrict__ Q, const float* __restrict__ K,
             const float* __restrict__ V, short* __restrict__ Qb,
             short* __restrict__ Kb, short* __restrict__ Vt) {
  __shared__ float fl[64][65];   // V transpose staging

  const int tid = threadIdx.x;
  const int t   = blockIdx.x;    // tile 0..31
  const int bh  = blockIdx.y;    // 0..31

  const size_t ibase = ((size_t)bh * S_LEN + t * 64) * D_HEAD;
  const float qscale = 0.125f * 1.44269504088896340736f;  // 1/sqrt(64)*log2(e)

  // Q convert+scale, K convert (natural layout), V load into LDS transpose.
#pragma unroll
  for (int i = 0; i < 4; ++i) {
    int e = (i * 256 + tid) * 4;
    int row = e >> 6, col = e & 63;
    size_t off = ibase + (size_t)row * D_HEAD + col;

    float4 q = *(const float4*)(Q + off);
    i32x2 wq;
    wq[0] = pk2bf(q.x * qscale, q.y * qscale);
    wq[1] = pk2bf(q.z * qscale, q.w * qscale);
    *(i32x2*)(Qb + off) = wq;

    float4 k = *(const float4*)(K + off);
    i32x2 wk;
    wk[0] = pk2bf(k.x, k.y);
    wk[1] = pk2bf(k.z, k.w);
    *(i32x2*)(Kb + off) = wk;

    float4 v = *(const float4*)(V + off);
    fl[col + 0][row] = v.x;
    fl[col + 1][row] = v.y;
    fl[col + 2][row] = v.z;
    fl[col + 3][row] = v.w;
  }
  __syncthreads();

  short* vt = Vt + ((size_t)(bh * NTILE + t) * 64) * 64;
#pragma unroll
  for (int i = 0; i < 4; ++i) {
    int e = (i * 256 + tid) * 4;
    int dd = e >> 6, kk = e & 63;
    i32x2 w;
    w[0] = pk2bf(fl[dd][kk + 0], fl[dd][kk + 1]);
    w[1] = pk2bf(fl[dd][kk + 2], fl[dd][kk + 3]);
    *(i32x2*)(vt + dd * 64 + kk) = w;
  }
}

// ---------------------------------------------------------------------------
// Main: barrier-free. 4 waves x 32 q per block; frags direct from global,
// register-double-buffered one tile ahead.
// ---------------------------------------------------------------------------
__global__ __launch_bounds__(256, 2)
void fa_fwd2(const short* __restrict__ Qb, const short* __restrict__ Kb,
             const short* __restrict__ Vt, float* __restrict__ Out) {
  __shared__ short Ps[TQ * LDSTR];   // [q][key] wave-private rows, 18432 B

  const int tid  = threadIdx.x;
  const int wid  = tid >> 6;
  const int lane = tid & 63;
  const int quad = lane >> 4;
  const int r    = lane & 15;
  const int qb   = 32 * wid;

  // XCD swizzle: all 16 q-tiles of one bh on one XCD (blocks round-robin).
  const int id   = blockIdx.x;
  const int xcd  = id & 7;
  const int slot = id >> 3;
  const int bh   = xcd * 4 + (slot >> 4);
  const int q0   = (slot & 15) * TQ;

  // ---- Q fragments (bf16, pre-scaled) ----
  const short* qg = Qb + (size_t)bh * S_LEN * D_HEAD;
  bfrag8 qf[2][2];
#pragma unroll
  for (int nt = 0; nt < 2; ++nt)
#pragma unroll
    for (int ks = 0; ks < 2; ++ks)
      qf[nt][ks] = *(const bfrag8*)(qg + (size_t)(q0 + qb + 16 * nt + r) * D_HEAD + 32 * ks + 8 * quad);

  // ---- per-lane fragment base pointers ----
  const short* kl = Kb + (size_t)bh * S_LEN * D_HEAD + r * 64 + quad * 8;
  const short* vl = Vt + (size_t)bh * NTILE * 64 * 64 + r * 64 + quad * 8;
  // frag addr: base + t*4096 + mt*1024 + ks*32

  bfrag8 afA[4][2], avA[4][2], afB[4][2], avB[4][2];

  auto loadA = [&](int t) {
    const short* kp = kl + t * 4096;
    const short* vp = vl + t * 4096;
#pragma unroll
    for (int mt = 0; mt < 4; ++mt)
#pragma unroll
      for (int ks = 0; ks < 2; ++ks) {
        afA[mt][ks] = *(const bfrag8*)(kp + mt * 1024 + ks * 32);
        avA[mt][ks] = *(const bfrag8*)(vp + mt * 1024 + ks * 32);
      }
  };
  auto loadB = [&](int t) {
    const short* kp = kl + t * 4096;
    const short* vp = vl + t * 4096;
#pragma unroll
    for (int mt = 0; mt < 4; ++mt)
#pragma unroll
      for (int ks = 0; ks < 2; ++ks) {
        afB[mt][ks] = *(const bfrag8*)(kp + mt * 1024 + ks * 32);
        avB[mt][ks] = *(const bfrag8*)(vp + mt * 1024 + ks * 32);
      }
  };

  f32x4 acc[4][2];   // Z^T: row d = 16*mt+4*quad+reg, col q = qb+16*nt+r
#pragma unroll
  for (int mt = 0; mt < 4; ++mt)
#pragma unroll
    for (int nt = 0; nt < 2; ++nt)
      acc[mt][nt] = (f32x4){0.f, 0.f, 0.f, 0.f};

  float lrun[2] = {0.f, 0.f};

  auto computeTile = [&](bfrag8 (&af)[4][2], bfrag8 (&av)[4][2]) {
    // ---- S^T = K * Q^T ----
    f32x4 st[4][2];
#pragma unroll
    for (int mt = 0; mt < 4; ++mt)
#pragma unroll
      for (int nt = 0; nt < 2; ++nt)
        st[mt][nt] = (f32x4){0.f, 0.f, 0.f, 0.f};
#pragma unroll
    for (int ks = 0; ks < 2; ++ks)
#pragma unroll
      for (int mt = 0; mt < 4; ++mt)
#pragma unroll
        for (int nt = 0; nt < 2; ++nt)
          st[mt][nt] = __builtin_amdgcn_mfma_f32_16x16x32_bf16(af[mt][ks], qf[nt][ks], st[mt][nt], 0, 0, 0);

    // ---- P = exp2(S^T), pack to Ps (fixed m=0; exact after 1/l) ----
#pragma unroll
    for (int nt = 0; nt < 2; ++nt) {
      float ssum = 0.f;
#pragma unroll
      for (int mt = 0; mt < 4; ++mt) {
        float p0 = fexp2(st[mt][nt][0]);
        float p1 = fexp2(st[mt][nt][1]);
        float p2 = fexp2(st[mt][nt][2]);
        float p3 = fexp2(st[mt][nt][3]);
        ssum += (p0 + p1) + (p2 + p3);
        i32x2 w;
        w[0] = pk2bf(p0, p1);
        w[1] = pk2bf(p2, p3);
        *(i32x2*)&Ps[(qb + 16 * nt + r) * LDSTR + 16 * mt + 4 * quad] = w;
      }
      lrun[nt] += ssum;
    }
    // Same-wave Ps write->read: lgkmcnt ordering, no barrier needed.

    // ---- Z^T += V^T * P^T ----
#pragma unroll
    for (int ks = 0; ks < 2; ++ks) {
      bfrag8 bp[2];
#pragma unroll
      for (int nt = 0; nt < 2; ++nt)
        bp[nt] = *(const bfrag8*)&Ps[(qb + 16 * nt + r) * LDSTR + quad * 8 + 32 * ks];
#pragma unroll
      for (int mt = 0; mt < 4; ++mt)
#pragma unroll
        for (int nt = 0; nt < 2; ++nt)
          acc[mt][nt] = __builtin_amdgcn_mfma_f32_16x16x32_bf16(av[mt][ks], bp[nt], acc[mt][nt], 0, 0, 0);
    }
  };

  loadA(0);
  for (int t = 0; t < NTILE; t += 2) {
    loadB(t + 1);                       // issue next tile's 16 loads, then compute
    computeTile(afA, avA);
    if (t + 2 < NTILE) loadA(t + 2);
    computeTile(afB, avB);
  }

  // ---- epilogue: reduce l across quads, out = Z^T / l ----
  const int bb = bh >> 4, hh = bh & 15;
#pragma unroll
  for (int nt = 0; nt < 2; ++nt) {
    float l = lrun[nt];
    l += __shfl_xor(l, 16);
    l += __shfl_xor(l, 32);
    float inv = 1.0f / l;
    int qg2 = q0 + qb + 16 * nt + r;
    float* op = Out + ((size_t)bb * S_LEN + qg2) * (NHEADS * D_HEAD) + hh * D_HEAD;
#pragma unroll
    for (int mt = 0; mt < 4; ++mt) {
      float4 o;
      o.x = acc[mt][nt][0] * inv; o.y = acc[mt][nt][1] * inv;
      o.z = acc[mt][nt][2] * inv; o.w = acc[mt][nt][3] * inv;
      *(float4*)(op + 16 * mt + 4 * quad) = o;
    }
  }
}

// ---------------------------------------------------------------------------
// Fallback (R6): single-pass double-buffered LDS version, if ws too small.
// ---------------------------------------------------------------------------
__global__ __launch_bounds__(256, 2)
void fa_fwd(const float* __restrict__ Q, const float* __restrict__ K,
            const float* __restrict__ V, float* __restrict__ Out) {
  __shared__ short Ks [2][TK * LDSTR];
  __shared__ short VsT[2][D_HEAD * LDSTR];
  __shared__ short Psf[TQ * LDSTR];

  const int tid  = threadIdx.x;
  const int wid  = tid >> 6;
  const int lane = tid & 63;
  const int quad = lane >> 4;
  const int r    = lane & 15;
  const int qb   = 32 * wid;

  const int bh = blockIdx.y;
  const int q0 = blockIdx.x * TQ;

  const float* Qg = Q + (size_t)bh * S_LEN * D_HEAD;
  const float* Kg = K + (size_t)bh * S_LEN * D_HEAD;
  const float* Vg = V + (size_t)bh * S_LEN * D_HEAD;

  const float qscale = 0.125f * 1.44269504088896340736f;

  bfrag8 qf[2][2];
#pragma unroll
  for (int nt = 0; nt < 2; ++nt)
#pragma unroll
    for (int ks = 0; ks < 2; ++ks) {
      const float* qp = Qg + (size_t)(q0 + qb + 16 * nt + r) * D_HEAD + 32 * ks + 8 * quad;
      float4 a = *(const float4*)qp;
      float4 b = *(const float4*)(qp + 4);
      i32x4 w;
      w[0] = pk2bf(a.x * qscale, a.y * qscale);
      w[1] = pk2bf(a.z * qscale, a.w * qscale);
      w[2] = pk2bf(b.x * qscale, b.y * qscale);
      w[3] = pk2bf(b.z * qscale, b.w * qscale);
      qf[nt][ks] = __builtin_bit_cast(bfrag8, w);
    }

  float4 kpre[4];
  float  vpre[16];

  auto load_tile = [&](int k0) {
#pragma unroll
    for (int i = 0; i < 4; ++i) {
      int e = (i * 256 + tid) * 4;
      kpre[i] = *(const float4*)(Kg + (size_t)(k0 + (e >> 6)) * D_HEAD + (e & 63));
    }
    const float* vpp = Vg + (size_t)(k0 + wid * 16) * D_HEAD + lane;
#pragma unroll
    for (int j = 0; j < 16; ++j) vpre[j] = vpp[(size_t)j * D_HEAD];
  };

  auto store_tile = [&](short* ksb, short* vsb) {
#pragma unroll
    for (int i = 0; i < 4; ++i) {
      int e = (i * 256 + tid) * 4;
      i32x2 w;
      w[0] = pk2bf(kpre[i].x, kpre[i].y);
      w[1] = pk2bf(kpre[i].z, kpre[i].w);
      *(i32x2*)&ksb[(e >> 6) * LDSTR + (e & 63)] = w;
    }
    i32x4 w0, w1;
#pragma unroll
    for (int j = 0; j < 4; ++j) w0[j] = pk2bf(vpre[2 * j],     vpre[2 * j + 1]);
#pragma unroll
    for (int j = 0; j < 4; ++j) w1[j] = pk2bf(vpre[8 + 2 * j], vpre[9 + 2 * j]);
    *(i32x4*)&vsb[lane * LDSTR + wid * 16]     = w0;
    *(i32x4*)&vsb[lane * LDSTR + wid * 16 + 8] = w1;
  };

  f32x4 acc[4][2];
#pragma unroll
  for (int mt = 0; mt < 4; ++mt)
#pragma unroll
    for (int nt = 0; nt < 2; ++nt)
      acc[mt][nt] = (f32x4){0.f, 0.f, 0.f, 0.f};

  float lrun[2] = {0.f, 0.f};

  auto compute = [&](const short* ksb, const short* vsb) {
    f32x4 st[4][2];
#pragma unroll
    for (int mt = 0; mt < 4; ++mt)
#pragma unroll
      for (int nt = 0; nt < 2; ++nt)
        st[mt][nt] = (f32x4){0.f, 0.f, 0.f, 0.f};
#pragma unroll
    for (int ks = 0; ks < 2; ++ks) {
      bfrag8 af[4];
#pragma unroll
      for (int mt = 0; mt < 4; ++mt)
        af[mt] = *(const bfrag8*)&ksb[(r + 16 * mt) * LDSTR + quad * 8 + 32 * ks];
#pragma unroll
      for (int mt = 0; mt < 4; ++mt)
#pragma unroll
        for (int nt = 0; nt < 2; ++nt)
          st[mt][nt] = __builtin_amdgcn_mfma_f32_16x16x32_bf16(af[mt], qf[nt][ks], st[mt][nt], 0, 0, 0);
    }
#pragma unroll
    for (int nt = 0; nt < 2; ++nt) {
      float ssum = 0.f;
#pragma unroll
      for (int mt = 0; mt < 4; ++mt) {
        float p0 = fexp2(st[mt][nt][0]);
        float p1 = fexp2(st[mt][nt][1]);
        float p2 = fexp2(st[mt][nt][2]);
        float p3 = fexp2(st[mt][nt][3]);
        ssum += (p0 + p1) + (p2 + p3);
        i32x2 w;
        w[0] = pk2bf(p0, p1);
        w[1] = pk2bf(p2, p3);
        *(i32x2*)&Psf[(qb + 16 * nt + r) * LDSTR + 16 * mt + 4 * quad] = w;
      }
      lrun[nt] += ssum;
    }
#pragma unroll
    for (int ks = 0; ks < 2; ++ks) {
      bfrag8 av[4], bp[2];
#pragma unroll
      for (int mt = 0; mt < 4; ++mt)
        av[mt] = *(const bfrag8*)&vsb[(r + 16 * mt) * LDSTR + quad * 8 + 32 * ks];
#pragma unroll
      for (int nt = 0; nt < 2; ++nt)
        bp[nt] = *(const bfrag8*)&Psf[(qb + 16 * nt + r) * LDSTR + quad * 8 + 32 * ks];
#pragma unroll
      for (int mt = 0; mt < 4; ++mt)
#pragma unroll
        for (int nt = 0; nt < 2; ++nt)
          acc[mt][nt] = __builtin_amdgcn_mfma_f32_16x16x32_bf16(av[mt], bp[nt], acc[mt][nt], 0, 0, 0);
    }
  };

  load_tile(0);
  store_tile(Ks[0], VsT[0]);
  load_tile(TK);

  for (int it = 0; it < NTILE; it += 2) {
    __syncthreads();
    compute(Ks[0], VsT[0]);
    store_tile(Ks[1], VsT[1]);
    if (it + 2 < NTILE) load_tile((it + 2) * TK);
    __syncthreads();
    compute(Ks[1], VsT[1]);
    if (it + 2 < NTILE) {
      store_tile(Ks[0], VsT[0]);
      if (it + 3 < NTILE) load_tile((it + 3) * TK);
    }
  }

  const int bb = bh >> 4, hh = bh & 15;
#pragma unroll
  for (int nt = 0; nt < 2; ++nt) {
    float l = lrun[nt];
    l += __shfl_xor(l, 16);
    l += __shfl_xor(l, 32);
    float inv = 1.0f / l;
    int qg2 = q0 + qb + 16 * nt + r;
    float* op = Out + ((size_t)bb * S_LEN + qg2) * (NHEADS * D_HEAD) + hh * D_HEAD;
#pragma unroll
    for (int mt = 0; mt < 4; ++mt) {
      float4 o;
      o.x = acc[mt][nt][0] * inv; o.y = acc[mt][nt][1] * inv;
      o.z = acc[mt][nt][2] * inv; o.w = acc[mt][nt][3] * inv;
      *(float4*)(op + 16 * mt + 4 * quad) = o;
    }
  }
}

extern "C" void kernel_launch(void* const* d_in, const int* in_sizes, int n_in,
                              void* d_out, int out_size, void* d_ws, size_t ws_size,
                              hipStream_t stream) {
  const float* Q = (const float*)d_in[0];
  const float* K = (const float*)d_in[1];
  const float* V = (const float*)d_in[2];
  float* O = (float*)d_out;

  const size_t nelem = (size_t)NBH * S_LEN * D_HEAD;        // 4.19M per tensor
  const size_t need  = 3 * nelem * sizeof(short);            // ~25.2 MB

  if (ws_size >= need) {
    short* Qb = (short*)d_ws;
    short* Kb = Qb + nelem;
    short* Vt = Kb + nelem;
    dim3 gp(NTILE, NBH);                 // 1024 blocks, memory-bound pre-pass
    fa_prep<<<gp, 256, 0, stream>>>(Q, K, V, Qb, Kb, Vt);
    fa_fwd2<<<dim3(512), 256, 0, stream>>>(Qb, Kb, Vt, O);
  } else {
    dim3 grid(S_LEN / TQ, NBH);
    fa_fwd<<<grid, 256, 0, stream>>>(Q, K, V, O);
  }
}

// Round 9
// 146.384 us; speedup vs baseline: 1.4229x; 1.4229x over previous
//
#include <hip/hip_runtime.h>
#include <cmath>

// Flash attention fwd, MI355X (gfx950).
// B=2 H=16 S=2048 D=64, fp32 in/out, bf16 MFMA 16x16x32 internally.
//
// R9: prep kernel writes K (natural) and V (transposed) as bf16 XOR-swizzled
//     8KB "LDS image" tiles in d_ws; main kernel stages them with
//     global_load_lds dwordx4 (no staging VALU / VGPRs / spills -- R8's
//     failure was a 240-VGPR budget vs 128 allocated -> scratch spills).
//     Single-barrier double-buffered K-loop (R6), XCD swizzle (R8, proven:
//     FETCH 139->12MB), m=0 softmax (R5, exact by shift-invariance).
//
// Swizzle: element (row, col) of a 64x64 tile lives at
//   row*64 + ((col>>3) ^ (row&7))*8 + (col&7)
// -> fragment b128 reads (8 lanes per 4-bank group, 2 per phase) conflict-free
//    without padding, so the tile is LDS-image-copyable by global_load_lds.
//
// Verified-layout MFMA (m89/m91/m120):
//   A[m=lane&15][k=(lane>>4)*8+j], B[k=(lane>>4)*8+j][n=lane&15],
//   C/D: col=lane&15, row=(lane>>4)*4+reg.

#define S_LEN   2048
#define D_HEAD  64
#define NHEADS  16
#define NBH     32
#define TQ      128   // queries per block
#define TK      64    // keys per tile
#define NTILE   (S_LEN / TK)   // 32
#define LDSTR   72    // Ps row stride (bf16 elems; padded, ds_write path)
#define TILE_SH 4096  // shorts per 64x64 bf16 tile

typedef short bfrag8 __attribute__((ext_vector_type(8)));  // 8 bf16 (A/B frag)
typedef float f32x4  __attribute__((ext_vector_type(4)));  // C/D frag
typedef int   i32x2  __attribute__((ext_vector_type(2)));
typedef int   i32x4  __attribute__((ext_vector_type(4)));

static __device__ __forceinline__ short f2bf(float f) {
  unsigned int u = __builtin_bit_cast(unsigned int, f);
  u = (u + 0x7fffu + ((u >> 16) & 1u)) >> 16;
  return (short)(unsigned short)u;
}

static __device__ __forceinline__ int pk2bf(float a, float b) {
#if __has_builtin(__builtin_amdgcn_cvt_pk_bf16_f32)
  typedef __bf16 bf16x2 __attribute__((ext_vector_type(2)));
  bf16x2 r = __builtin_amdgcn_cvt_pk_bf16_f32(a, b);
  return __builtin_bit_cast(int, r);
#else
  return (int)(unsigned short)f2bf(a) | ((int)(unsigned short)f2bf(b) << 16);
#endif
}

static __device__ __forceinline__ float fexp2(float x) {
#if __has_builtin(__builtin_amdgcn_exp2f)
  return __builtin_amdgcn_exp2f(x);   // v_exp_f32
#else
  return exp2f(x);
#endif
}

// async global->LDS, 16B/lane: dest = lds base (wave-uniform) + lane*16.
static __device__ __forceinline__ void gload_lds16(const short* g, short* l) {
  __builtin_amdgcn_global_load_lds(
      (const __attribute__((address_space(1))) void*)g,
      (__attribute__((address_space(3))) void*)l, 16, 0, 0);
}

// ---------------------------------------------------------------------------
// Pre-pass: per (tile, bh) write swizzled bf16 tiles.
//   Kt[bh][t]: (key,d)  at key*64 + ((d>>3)^(key&7))*8 + (d&7)
//   Vt[bh][t]: (d,key)  at d*64   + ((key>>3)^(d&7))*8 + (key&7)
// XCD-swizzled grid so tiles are written by the XCD that later reads them.
// ---------------------------------------------------------------------------
__global__ __launch_bounds__(256)
void fa_prep(const float* __restrict__ K, const float* __restrict__ V,
             short* __restrict__ Kt, short* __restrict__ Vt) {
  __shared__ float fl[64][65];   // V transpose staging

  const int tid = threadIdx.x;
  const int id  = blockIdx.x;          // 0..1023
  const int xcd = id & 7;
  const int s   = id >> 3;             // 0..127
  const int bh  = xcd * 4 + (s >> 5);  // 4 bh per XCD
  const int t   = s & 31;

  const size_t ibase = ((size_t)bh * S_LEN + t * 64) * D_HEAD;
  short* kt = Kt + (size_t)(bh * NTILE + t) * TILE_SH;
  short* vt = Vt + (size_t)(bh * NTILE + t) * TILE_SH;

  // ---- K: convert + swizzle (no transpose) ----
#pragma unroll
  for (int p = 0; p < 2; ++p) {
    int idx = p * 256 + tid;           // 0..511 chunk index
    int key = idx >> 3, c = idx & 7;
    const float* src = K + ibase + key * 64 + c * 8;
    float4 a = *(const float4*)src;
    float4 b = *(const float4*)(src + 4);
    i32x4 w;
    w[0] = pk2bf(a.x, a.y); w[1] = pk2bf(a.z, a.w);
    w[2] = pk2bf(b.x, b.y); w[3] = pk2bf(b.z, b.w);
    *(i32x4*)(kt + key * 64 + ((c ^ (key & 7)) * 8)) = w;
  }

  // ---- V: load fp32 tile into LDS (transposed), then swizzle-write ----
#pragma unroll
  for (int i = 0; i < 4; ++i) {
    int e = (i * 256 + tid) * 4;
    int row = e >> 6, col = e & 63;
    float4 v = *(const float4*)(V + ibase + (size_t)row * 64 + col);
    fl[col + 0][row] = v.x;
    fl[col + 1][row] = v.y;
    fl[col + 2][row] = v.z;
    fl[col + 3][row] = v.w;
  }
  __syncthreads();
#pragma unroll
  for (int p = 0; p < 2; ++p) {
    int idx = p * 256 + tid;
    int d = idx >> 3, ck = idx & 7;
    const float* row = &fl[d][ck * 8];
    i32x4 w;
    w[0] = pk2bf(row[0], row[1]); w[1] = pk2bf(row[2], row[3]);
    w[2] = pk2bf(row[4], row[5]); w[3] = pk2bf(row[6], row[7]);
    *(i32x4*)(vt + d * 64 + ((ck ^ (d & 7)) * 8)) = w;
  }
}

// ---------------------------------------------------------------------------
// Main kernel: single-barrier dbuf, global_load_lds staging, swizzled frags.
// ---------------------------------------------------------------------------
__global__ __launch_bounds__(256, 2)
void fa_fwd3(const float* __restrict__ Q, const short* __restrict__ Kt,
             const short* __restrict__ Vt, float* __restrict__ Out) {
  __shared__ short Ksb[2][TILE_SH];   // swizzled [key][d] images, 2 x 8192 B
  __shared__ short Vsb[2][TILE_SH];   // swizzled [d][key] images, 2 x 8192 B
  __shared__ short Ps [TQ * LDSTR];   // [q][key] wave-private rows, 18432 B

  const int tid  = threadIdx.x;
  const int wid  = tid >> 6;
  const int lane = tid & 63;
  const int quad = lane >> 4;
  const int r    = lane & 15;
  const int rk   = r & 7;
  const int qb   = 32 * wid;

  // XCD swizzle: 16 q-tiles of one bh on one XCD.
  const int id   = blockIdx.x;
  const int xcd  = id & 7;
  const int slot = id >> 3;
  const int bh   = xcd * 4 + (slot >> 4);
  const int q0   = (slot & 15) * TQ;

  const float qscale = 0.125f * 1.44269504088896340736f;  // 1/sqrt(64)*log2(e)

  // ---- Q fragments from fp32 global (loop-invariant) ----
  const float* Qg = Q + (size_t)bh * S_LEN * D_HEAD;
  bfrag8 qf[2][2];
#pragma unroll
  for (int nt = 0; nt < 2; ++nt)
#pragma unroll
    for (int ks = 0; ks < 2; ++ks) {
      const float* qp = Qg + (size_t)(q0 + qb + 16 * nt + r) * D_HEAD + 32 * ks + 8 * quad;
      float4 a = *(const float4*)qp;
      float4 b = *(const float4*)(qp + 4);
      i32x4 w;
      w[0] = pk2bf(a.x * qscale, a.y * qscale);
      w[1] = pk2bf(a.z * qscale, a.w * qscale);
      w[2] = pk2bf(b.x * qscale, b.y * qscale);
      w[3] = pk2bf(b.z * qscale, b.w * qscale);
      qf[nt][ks] = __builtin_bit_cast(bfrag8, w);
    }

  const short* ktb = Kt + (size_t)bh * NTILE * TILE_SH;
  const short* vtb = Vt + (size_t)bh * NTILE * TILE_SH;

  // stage tile t into buffer b: 4 global_load_lds per wave (2 K + 2 V).
  auto stage = [&](int b, int t) {
    const short* ks = ktb + (size_t)t * TILE_SH;
    const short* vs = vtb + (size_t)t * TILE_SH;
#pragma unroll
    for (int n = 0; n < 2; ++n) {
      int ch = (wid * 2 + n) * 512;          // 1KB chunk per issue
      gload_lds16(ks + ch + lane * 8, &Ksb[b][ch]);
      gload_lds16(vs + ch + lane * 8, &Vsb[b][ch]);
    }
  };

  f32x4 acc[4][2];   // Z^T: row d = 16*mt+4*quad+reg, col q = qb+16*nt+r
#pragma unroll
  for (int mt = 0; mt < 4; ++mt)
#pragma unroll
    for (int nt = 0; nt < 2; ++nt)
      acc[mt][nt] = (f32x4){0.f, 0.f, 0.f, 0.f};

  float lrun[2] = {0.f, 0.f};

  auto compute = [&](const short* ksb, const short* vsb) {
    // ---- S^T = K * Q^T ----
    f32x4 st[4][2];
#pragma unroll
    for (int mt = 0; mt < 4; ++mt)
#pragma unroll
      for (int nt = 0; nt < 2; ++nt)
        st[mt][nt] = (f32x4){0.f, 0.f, 0.f, 0.f};

#pragma unroll
    for (int ks = 0; ks < 2; ++ks) {
      bfrag8 af[4];
#pragma unroll
      for (int mt = 0; mt < 4; ++mt)
        af[mt] = *(const bfrag8*)&ksb[(r + 16 * mt) * 64 + (((quad + 4 * ks) ^ rk) * 8)];
#pragma unroll
      for (int mt = 0; mt < 4; ++mt)
#pragma unroll
        for (int nt = 0; nt < 2; ++nt)
          st[mt][nt] = __builtin_amdgcn_mfma_f32_16x16x32_bf16(af[mt], qf[nt][ks], st[mt][nt], 0, 0, 0);
    }

    // ---- P = exp2(S^T) (m=0 fixed; exact after final 1/l) ----
#pragma unroll
    for (int nt = 0; nt < 2; ++nt) {
      float ssum = 0.f;
#pragma unroll
      for (int mt = 0; mt < 4; ++mt) {
        float p0 = fexp2(st[mt][nt][0]);
        float p1 = fexp2(st[mt][nt][1]);
        float p2 = fexp2(st[mt][nt][2]);
        float p3 = fexp2(st[mt][nt][3]);
        ssum += (p0 + p1) + (p2 + p3);
        i32x2 w;
        w[0] = pk2bf(p0, p1);
        w[1] = pk2bf(p2, p3);
        *(i32x2*)&Ps[(qb + 16 * nt + r) * LDSTR + 16 * mt + 4 * quad] = w;
      }
      lrun[nt] += ssum;
    }
    // Same-wave Ps write->read: lgkmcnt ordering, no barrier.

    // ---- Z^T += V^T * P^T ----
#pragma unroll
    for (int ks = 0; ks < 2; ++ks) {
      bfrag8 av[4], bp[2];
#pragma unroll
      for (int mt = 0; mt < 4; ++mt)
        av[mt] = *(const bfrag8*)&vsb[(r + 16 * mt) * 64 + (((quad + 4 * ks) ^ rk) * 8)];
#pragma unroll
      for (int nt = 0; nt < 2; ++nt)
        bp[nt] = *(const bfrag8*)&Ps[(qb + 16 * nt + r) * LDSTR + quad * 8 + 32 * ks];
#pragma unroll
      for (int mt = 0; mt < 4; ++mt)
#pragma unroll
        for (int nt = 0; nt < 2; ++nt)
          acc[mt][nt] = __builtin_amdgcn_mfma_f32_16x16x32_bf16(av[mt][0] == av[mt][0] ? av[mt] : av[mt], bp[nt], acc[mt][nt], 0, 0, 0);
    }
  };

  // ---- pipeline: stage 0 -> barrier -> {stage next, compute} ----
  stage(0, 0);
  for (int t = 0; t < NTILE; t += 2) {
    __syncthreads();                 // buf0 (tile t) loads drained + visible
    stage(1, t + 1);                 // t+1 <= 31 always
    compute(Ksb[0], Vsb[0]);
    __syncthreads();                 // buf1 (tile t+1) visible
    if (t + 2 < NTILE) stage(0, t + 2);
    compute(Ksb[1], Vsb[1]);
  }

  // ---- epilogue ----
  const int bb = bh >> 4, hh = bh & 15;
#pragma unroll
  for (int nt = 0; nt < 2; ++nt) {
    float l = lrun[nt];
    l += __shfl_xor(l, 16);
    l += __shfl_xor(l, 32);
    float inv = 1.0f / l;
    int qg = q0 + qb + 16 * nt + r;
    float* op = Out + ((size_t)bb * S_LEN + qg) * (NHEADS * D_HEAD) + hh * D_HEAD;
#pragma unroll
    for (int mt = 0; mt < 4; ++mt) {
      float4 o;
      o.x = acc[mt][nt][0] * inv; o.y = acc[mt][nt][1] * inv;
      o.z = acc[mt][nt][2] * inv; o.w = acc[mt][nt][3] * inv;
      *(float4*)(op + 16 * mt + 4 * quad) = o;
    }
  }
}

// ---------------------------------------------------------------------------
// Fallback (R6): single-pass double-buffered LDS version, if ws too small.
// ---------------------------------------------------------------------------
__global__ __launch_bounds__(256, 2)
void fa_fwd(const float* __restrict__ Q, const float* __restrict__ K,
            const float* __restrict__ V, float* __restrict__ Out) {
  __shared__ short Ks [2][TK * LDSTR];
  __shared__ short VsT[2][D_HEAD * LDSTR];
  __shared__ short Psf[TQ * LDSTR];

  const int tid  = threadIdx.x;
  const int wid  = tid >> 6;
  const int lane = tid & 63;
  const int quad = lane >> 4;
  const int r    = lane & 15;
  const int qb   = 32 * wid;

  const int bh = blockIdx.y;
  const int q0 = blockIdx.x * TQ;

  const float* Qg = Q + (size_t)bh * S_LEN * D_HEAD;
  const float* Kg = K + (size_t)bh * S_LEN * D_HEAD;
  const float* Vg = V + (size_t)bh * S_LEN * D_HEAD;

  const float qscale = 0.125f * 1.44269504088896340736f;

  bfrag8 qf[2][2];
#pragma unroll
  for (int nt = 0; nt < 2; ++nt)
#pragma unroll
    for (int ks = 0; ks < 2; ++ks) {
      const float* qp = Qg + (size_t)(q0 + qb + 16 * nt + r) * D_HEAD + 32 * ks + 8 * quad;
      float4 a = *(const float4*)qp;
      float4 b = *(const float4*)(qp + 4);
      i32x4 w;
      w[0] = pk2bf(a.x * qscale, a.y * qscale);
      w[1] = pk2bf(a.z * qscale, a.w * qscale);
      w[2] = pk2bf(b.x * qscale, b.y * qscale);
      w[3] = pk2bf(b.z * qscale, b.w * qscale);
      qf[nt][ks] = __builtin_bit_cast(bfrag8, w);
    }

  float4 kpre[4];
  float  vpre[16];

  auto load_tile = [&](int k0) {
#pragma unroll
    for (int i = 0; i < 4; ++i) {
      int e = (i * 256 + tid) * 4;
      kpre[i] = *(const float4*)(Kg + (size_t)(k0 + (e >> 6)) * D_HEAD + (e & 63));
    }
    const float* vpp = Vg + (size_t)(k0 + wid * 16) * D_HEAD + lane;
#pragma unroll
    for (int j = 0; j < 16; ++j) vpre[j] = vpp[(size_t)j * D_HEAD];
  };

  auto store_tile = [&](short* ksb, short* vsb) {
#pragma unroll
    for (int i = 0; i < 4; ++i) {
      int e = (i * 256 + tid) * 4;
      i32x2 w;
      w[0] = pk2bf(kpre[i].x, kpre[i].y);
      w[1] = pk2bf(kpre[i].z, kpre[i].w);
      *(i32x2*)&ksb[(e >> 6) * LDSTR + (e & 63)] = w;
    }
    i32x4 w0, w1;
#pragma unroll
    for (int j = 0; j < 4; ++j) w0[j] = pk2bf(vpre[2 * j],     vpre[2 * j + 1]);
#pragma unroll
    for (int j = 0; j < 4; ++j) w1[j] = pk2bf(vpre[8 + 2 * j], vpre[9 + 2 * j]);
    *(i32x4*)&vsb[lane * LDSTR + wid * 16]     = w0;
    *(i32x4*)&vsb[lane * LDSTR + wid * 16 + 8] = w1;
  };

  f32x4 acc[4][2];
#pragma unroll
  for (int mt = 0; mt < 4; ++mt)
#pragma unroll
    for (int nt = 0; nt < 2; ++nt)
      acc[mt][nt] = (f32x4){0.f, 0.f, 0.f, 0.f};

  float lrun[2] = {0.f, 0.f};

  auto compute = [&](const short* ksb, const short* vsb) {
    f32x4 st[4][2];
#pragma unroll
    for (int mt = 0; mt < 4; ++mt)
#pragma unroll
      for (int nt = 0; nt < 2; ++nt)
        st[mt][nt] = (f32x4){0.f, 0.f, 0.f, 0.f};
#pragma unroll
    for (int ks = 0; ks < 2; ++ks) {
      bfrag8 af[4];
#pragma unroll
      for (int mt = 0; mt < 4; ++mt)
        af[mt] = *(const bfrag8*)&ksb[(r + 16 * mt) * LDSTR + quad * 8 + 32 * ks];
#pragma unroll
      for (int mt = 0; mt < 4; ++mt)
#pragma unroll
        for (int nt = 0; nt < 2; ++nt)
          st[mt][nt] = __builtin_amdgcn_mfma_f32_16x16x32_bf16(af[mt], qf[nt][ks], st[mt][nt], 0, 0, 0);
    }
#pragma unroll
    for (int nt = 0; nt < 2; ++nt) {
      float ssum = 0.f;
#pragma unroll
      for (int mt = 0; mt < 4; ++mt) {
        float p0 = fexp2(st[mt][nt][0]);
        float p1 = fexp2(st[mt][nt][1]);
        float p2 = fexp2(st[mt][nt][2]);
        float p3 = fexp2(st[mt][nt][3]);
        ssum += (p0 + p1) + (p2 + p3);
        i32x2 w;
        w[0] = pk2bf(p0, p1);
        w[1] = pk2bf(p2, p3);
        *(i32x2*)&Psf[(qb + 16 * nt + r) * LDSTR + 16 * mt + 4 * quad] = w;
      }
      lrun[nt] += ssum;
    }
#pragma unroll
    for (int ks = 0; ks < 2; ++ks) {
      bfrag8 av[4], bp[2];
#pragma unroll
      for (int mt = 0; mt < 4; ++mt)
        av[mt] = *(const bfrag8*)&vsb[(r + 16 * mt) * LDSTR + quad * 8 + 32 * ks];
#pragma unroll
      for (int nt = 0; nt < 2; ++nt)
        bp[nt] = *(const bfrag8*)&Psf[(qb + 16 * nt + r) * LDSTR + quad * 8 + 32 * ks];
#pragma unroll
      for (int mt = 0; mt < 4; ++mt)
#pragma unroll
        for (int nt = 0; nt < 2; ++nt)
          acc[mt][nt] = __builtin_amdgcn_mfma_f32_16x16x32_bf16(av[mt], bp[nt], acc[mt][nt], 0, 0, 0);
    }
  };

  load_tile(0);
  store_tile(Ks[0], VsT[0]);
  load_tile(TK);

  for (int it = 0; it < NTILE; it += 2) {
    __syncthreads();
    compute(Ks[0], VsT[0]);
    store_tile(Ks[1], VsT[1]);
    if (it + 2 < NTILE) load_tile((it + 2) * TK);
    __syncthreads();
    compute(Ks[1], VsT[1]);
    if (it + 2 < NTILE) {
      store_tile(Ks[0], VsT[0]);
      if (it + 3 < NTILE) load_tile((it + 3) * TK);
    }
  }

  const int bb = bh >> 4, hh = bh & 15;
#pragma unroll
  for (int nt = 0; nt < 2; ++nt) {
    float l = lrun[nt];
    l += __shfl_xor(l, 16);
    l += __shfl_xor(l, 32);
    float inv = 1.0f / l;
    int qg = q0 + qb + 16 * nt + r;
    float* op = Out + ((size_t)bb * S_LEN + qg) * (NHEADS * D_HEAD) + hh * D_HEAD;
#pragma unroll
    for (int mt = 0; mt < 4; ++mt) {
      float4 o;
      o.x = acc[mt][nt][0] * inv; o.y = acc[mt][nt][1] * inv;
      o.z = acc[mt][nt][2] * inv; o.w = acc[mt][nt][3] * inv;
      *(float4*)(op + 16 * mt + 4 * quad) = o;
    }
  }
}

extern "C" void kernel_launch(void* const* d_in, const int* in_sizes, int n_in,
                              void* d_out, int out_size, void* d_ws, size_t ws_size,
                              hipStream_t stream) {
  const float* Q = (const float*)d_in[0];
  const float* K = (const float*)d_in[1];
  const float* V = (const float*)d_in[2];
  float* O = (float*)d_out;

  const size_t telems = (size_t)NBH * NTILE * TILE_SH;   // 4.19M shorts per tensor
  const size_t need   = 2 * telems * sizeof(short);      // 16 MB

  if (ws_size >= need) {
    short* Kt = (short*)d_ws;
    short* Vt = Kt + telems;
    fa_prep<<<dim3(NBH * NTILE), 256, 0, stream>>>(K, V, Kt, Vt);
    fa_fwd3<<<dim3(512), 256, 0, stream>>>(Q, Kt, Vt, O);
  } else {
    dim3 grid(S_LEN / TQ, NBH);
    fa_fwd<<<grid, 256, 0, stream>>>(Q, K, V, O);
  }
}